// Round 8
// baseline (98.678 us; speedup 1.0000x reference)
//
#include <hip/hip_runtime.h>
#include <hip/hip_bf16.h>

#define NB2    1024      // 2*BATCH
#define FS1    10
#define FS2    25
#define FD     256
#define FH     256
#define MAXDEG 128

typedef __attribute__((ext_vector_type(8))) short bf16x8;
typedef __attribute__((ext_vector_type(4))) float f32x4;

__device__ inline ushort f2bf(float f) {
    union { float f; unsigned u; } v; v.f = f;
    unsigned u = v.u;
    unsigned r = (u + 0x7FFFu + ((u >> 16) & 1u)) >> 16;   // round-to-nearest-even
    return (ushort)r;
}
__device__ inline float bf2f(ushort h) {
    union { unsigned u; float f; } v; v.u = ((unsigned)h) << 16;
    return v.f;
}

// ---------------- K1: fused prep — weight transpose+cast AND sampling ----------------
__global__ void prep_kernel(const float* __restrict__ Ws1, const float* __restrict__ Wn1,
                            const float* __restrict__ Ws2, const float* __restrict__ Wn2,
                            ushort* __restrict__ Wt_s1, ushort* __restrict__ Wt_n1,
                            ushort* __restrict__ Wt_s2, ushort* __restrict__ Wt_n2,
                            const int* __restrict__ batch1, const int* __restrict__ batch2,
                            const int* __restrict__ adj,
                            const int* __restrict__ col1, const int* __restrict__ col2,
                            int* __restrict__ nodes, int* __restrict__ s1,
                            int* __restrict__ s2)
{
    int b = blockIdx.x;
    if (b < 1536) {
        int t = b * 256 + threadIdx.x;          // [0, 393216)
        const float* W; ushort* Wt; int K; int base;
        if (t < 131072) {
            K = 256;
            if (t < 65536) { W = Ws1; Wt = Wt_s1; base = 0; }
            else           { W = Wn1; Wt = Wt_n1; base = 65536; }
        } else {
            K = 512;
            if (t < 262144) { W = Ws2; Wt = Wt_s2; base = 131072; }
            else            { W = Wn2; Wt = Wt_n2; base = 262144; }
        }
        int tt = t - base;
        int k = tt >> 8;          // N = 256
        int n = tt & 255;
        Wt[(long)n * K + k] = f2bf(W[tt]);
    } else {
        int t2 = (b - 1536) * 256 + threadIdx.x;   // [0, 256000)
        int i  = t2 / FS2;                          // s1 index [0,10240)
        int ns = i / FS1;                           // node slot [0,1024)
        int node = (ns < 512) ? batch1[ns] : batch2[ns - 512];
        int s1v = adj[(long)node * MAXDEG + col1[i]];
        s2[t2] = adj[(long)s1v * MAXDEG + col2[t2]];
        if (t2 - i * FS2 == 0) {
            s1[i] = s1v;
            if (i - ns * FS1 == 0) nodes[ns] = node;
        }
    }
}

// ---------------- gather-mean body (burst loads) ----------------
template<int F>
__device__ __forceinline__ void mean_body(const float* __restrict__ src,
                                          const int* __restrict__ idx,
                                          ushort* __restrict__ dst,
                                          int g, int l)
{
    const int* ip = idx + (long)g * F;
    int r[F];
    #pragma unroll
    for (int j = 0; j < F; ++j) r[j] = ip[j];

    float4 acc[4];
    #pragma unroll
    for (int q = 0; q < 4; ++q) acc[q] = make_float4(0.f, 0.f, 0.f, 0.f);

    #pragma unroll
    for (int j0 = 0; j0 < F; j0 += 8) {
        float4 v[8];
        #pragma unroll
        for (int u = 0; u < 8; ++u)
            if (j0 + u < F)
                v[u] = *((const float4*)(src + (long)r[j0 + u] * FD) + l);
        #pragma unroll
        for (int u = 0; u < 8; ++u)
            if (j0 + u < F) {
                int q = u & 3;
                acc[q].x += v[u].x; acc[q].y += v[u].y;
                acc[q].z += v[u].z; acc[q].w += v[u].w;
            }
    }
    float s = 1.0f / F;
    float sx = (acc[0].x + acc[1].x + acc[2].x + acc[3].x) * s;
    float sy = (acc[0].y + acc[1].y + acc[2].y + acc[3].y) * s;
    float sz = (acc[0].z + acc[1].z + acc[2].z + acc[3].z) * s;
    float sw = (acc[0].w + acc[1].w + acc[2].w + acc[3].w) * s;
    uint2 o;
    o.x = (unsigned)f2bf(sx) | ((unsigned)f2bf(sy) << 16);
    o.y = (unsigned)f2bf(sz) | ((unsigned)f2bf(sw) << 16);
    *((uint2*)(dst + (long)g * FD) + l) = o;
}

// ---------------- GEMM wave bodies (16 rows x 64 cols per wave) ----------------
// A-self: features fp32 row-gather, cast in-reg. K=256.
__device__ __forceinline__ void l1gemm_self_wave(const float* __restrict__ features,
                                                 const int* __restrict__ idx,
                                                 const ushort* __restrict__ Bt,
                                                 ushort* __restrict__ C,
                                                 int r0, int cs, int coff,
                                                 int m16, int g)
{
    const int row = r0 + m16;
    const long arow = (long)idx[row];

    f32x4 acc[4];
    #pragma unroll
    for (int j = 0; j < 4; ++j) acc[j] = (f32x4){0.f, 0.f, 0.f, 0.f};

    #pragma unroll
    for (int k0 = 0; k0 < 256; k0 += 32) {
        const float* p = features + arow * FD + k0 + g * 8;
        float4 v0 = *(const float4*)p;
        float4 v1 = *(const float4*)(p + 4);
        bf16x8 a;
        a[0] = (short)f2bf(v0.x); a[1] = (short)f2bf(v0.y);
        a[2] = (short)f2bf(v0.z); a[3] = (short)f2bf(v0.w);
        a[4] = (short)f2bf(v1.x); a[5] = (short)f2bf(v1.y);
        a[6] = (short)f2bf(v1.z); a[7] = (short)f2bf(v1.w);
        #pragma unroll
        for (int j = 0; j < 4; ++j) {
            bf16x8 bf = *(const bf16x8*)(Bt + (long)(cs * 64 + j * 16 + m16) * 256 + k0 + g * 8);
            acc[j] = __builtin_amdgcn_mfma_f32_16x16x32_bf16(a, bf, acc[j], 0, 0, 0);
        }
    }
    #pragma unroll
    for (int j = 0; j < 4; ++j)
        #pragma unroll
        for (int r = 0; r < 4; ++r)
            C[(long)(r0 + g * 4 + r) * 512 + coff + cs * 64 + j * 16 + m16] =
                f2bf(fmaxf(acc[j][r], 0.f));
}

// A-neigh: bf16 contiguous rows. K=256, relu.
__device__ __forceinline__ void l1gemm_neigh_wave(const ushort* __restrict__ An,
                                                  const ushort* __restrict__ Bt,
                                                  ushort* __restrict__ C,
                                                  int r0, int cs, int coff,
                                                  int m16, int g)
{
    const int row = r0 + m16;
    f32x4 acc[4];
    #pragma unroll
    for (int j = 0; j < 4; ++j) acc[j] = (f32x4){0.f, 0.f, 0.f, 0.f};

    #pragma unroll
    for (int k0 = 0; k0 < 256; k0 += 32) {
        bf16x8 a = *(const bf16x8*)(An + (long)row * FD + k0 + g * 8);
        #pragma unroll
        for (int j = 0; j < 4; ++j) {
            bf16x8 bf = *(const bf16x8*)(Bt + (long)(cs * 64 + j * 16 + m16) * 256 + k0 + g * 8);
            acc[j] = __builtin_amdgcn_mfma_f32_16x16x32_bf16(a, bf, acc[j], 0, 0, 0);
        }
    }
    #pragma unroll
    for (int j = 0; j < 4; ++j)
        #pragma unroll
        for (int r = 0; r < 4; ++r)
            C[(long)(r0 + g * 4 + r) * 512 + coff + cs * 64 + j * 16 + m16] =
                f2bf(fmaxf(acc[j][r], 0.f));
}

// layer-2 K-split wave: K-chunk kh (128 wide), fp32 partial out.
__device__ __forceinline__ void l2gemm_wave(const ushort* __restrict__ A,
                                            const ushort* __restrict__ Bt,
                                            float* __restrict__ op,
                                            int r0, int cs, int kh, int coff,
                                            int m16, int g)
{
    const int row = r0 + m16;
    const int kb  = kh * 128;
    f32x4 acc[4];
    #pragma unroll
    for (int j = 0; j < 4; ++j) acc[j] = (f32x4){0.f, 0.f, 0.f, 0.f};

    #pragma unroll
    for (int ks = 0; ks < 128; ks += 32) {
        int k = kb + ks;
        bf16x8 a = *(const bf16x8*)(A + (long)row * 512 + k + g * 8);
        #pragma unroll
        for (int j = 0; j < 4; ++j) {
            bf16x8 bf = *(const bf16x8*)(Bt + (long)(cs * 64 + j * 16 + m16) * 512 + k + g * 8);
            acc[j] = __builtin_amdgcn_mfma_f32_16x16x32_bf16(a, bf, acc[j], 0, 0, 0);
        }
    }
    #pragma unroll
    for (int j = 0; j < 4; ++j)
        #pragma unroll
        for (int r = 0; r < 4; ++r)
            op[(long)(r0 + g * 4 + r) * 512 + coff + cs * 64 + j * 16 + m16] = acc[j][r];
}

// ---------------- K2: means + layer-1 SELF GEMMs (independent, co-scheduled) ----
// b<2560: s2-mean; b<2816: s1-mean; b<3520: l1 self-GEMM (704 blocks = 2816 waves)
__global__ void k2_means_l1self(const float* __restrict__ features,
                                const int* __restrict__ s2, const int* __restrict__ s1,
                                const int* __restrict__ nodes,
                                ushort* __restrict__ nm2, ushort* __restrict__ nm1,
                                const ushort* __restrict__ Wt_s1,
                                ushort* __restrict__ h1n, ushort* __restrict__ h0n)
{
    int b = blockIdx.x;
    int wave = threadIdx.x >> 6;
    int l = threadIdx.x & 63;
    if (b < 2560) { mean_body<FS2>(features, s2, nm2, b * 4 + wave, l); return; }
    if (b < 2816) { mean_body<FS1>(features, s1, nm1, (b - 2816 + 256) * 4 + wave, l); return; }
    int u = (b - 2816) * 4 + wave;       // [0, 2816)
    int cs = u & 3;
    int t = u >> 2;                      // [0, 704)
    int m16 = l & 15, g = l >> 4;
    if (t < 640) l1gemm_self_wave(features, s1,    Wt_s1, h1n, t * 16,        cs, 0, m16, g);
    else         l1gemm_self_wave(features, nodes, Wt_s1, h0n, (t - 640) * 16, cs, 0, m16, g);
}

// ---------------- K3: layer-1 NEIGH GEMMs (needs nm2, nm1) ----------------
// 704 blocks = 2816 waves
__global__ void k3_l1neigh(const ushort* __restrict__ nm2, const ushort* __restrict__ nm1,
                           const ushort* __restrict__ Wt_n1,
                           ushort* __restrict__ h1n, ushort* __restrict__ h0n)
{
    int u = blockIdx.x * 4 + (threadIdx.x >> 6);   // [0, 2816)
    int l = threadIdx.x & 63;
    int cs = u & 3;
    int t = u >> 2;
    int m16 = l & 15, g = l >> 4;
    if (t < 640) l1gemm_neigh_wave(nm2, Wt_n1, h1n, t * 16,        cs, 256, m16, g);
    else         l1gemm_neigh_wave(nm1, Wt_n1, h0n, (t - 640) * 16, cs, 256, m16, g);
}

// ---------------- K4: layer-2 neighbor-mean + layer-2 SELF GEMM ----------------
// b<256: mean over groups of 10 h1n rows -> ml2 ; b<512: l2 self GEMM (K-split x4)
__global__ void k4_ml2_l2self(const ushort* __restrict__ h1n, ushort* __restrict__ ml2,
                              const ushort* __restrict__ h0n,
                              const ushort* __restrict__ Wt_s2,
                              float* __restrict__ opre)
{
    int b = blockIdx.x;
    int wave = threadIdx.x >> 6;
    int l = threadIdx.x & 63;
    if (b < 256) {
        int gp = b * 4 + wave;      // [0,1024)
        float acc[8] = {};
        for (int j = 0; j < FS1; ++j) {
            uint4 v = *((const uint4*)(h1n + ((long)gp * FS1 + j) * 512) + l);
            unsigned wd[4] = { v.x, v.y, v.z, v.w };
            #pragma unroll
            for (int q = 0; q < 4; ++q) {
                acc[2 * q]     += bf2f((ushort)(wd[q] & 0xFFFF));
                acc[2 * q + 1] += bf2f((ushort)(wd[q] >> 16));
            }
        }
        float s = 1.0f / FS1;
        uint4 o;
        unsigned* ow = (unsigned*)&o;
        #pragma unroll
        for (int q = 0; q < 4; ++q)
            ow[q] = (unsigned)f2bf(acc[2 * q] * s) | ((unsigned)f2bf(acc[2 * q + 1] * s) << 16);
        *((uint4*)(ml2 + (long)gp * 512) + l) = o;
        return;
    }
    int u = (b - 256) * 4 + wave;   // [0,1024)
    int kh = u & 3, cs = (u >> 2) & 3, rt = u >> 4;
    int m16 = l & 15, g = l >> 4;
    l2gemm_wave(h0n, Wt_s2, opre + (long)kh * NB2 * 512, rt * 16, cs, kh, 0, m16, g);
}

// ---------------- K5: layer-2 NEIGH GEMM (needs ml2) ----------------
__global__ void k5_l2neigh(const ushort* __restrict__ ml2,
                           const ushort* __restrict__ Wt_n2,
                           float* __restrict__ opre)
{
    int u = blockIdx.x * 4 + (threadIdx.x >> 6);   // [0,1024)
    int l = threadIdx.x & 63;
    int kh = u & 3, cs = (u >> 2) & 3, rt = u >> 4;
    int m16 = l & 15, g = l >> 4;
    l2gemm_wave(ml2, Wt_n2, opre + (long)kh * NB2 * 512, rt * 16, cs, kh, 256, m16, g);
}

// ---------------- K6: row L2 normalize (sums 4 K-split partials) ----------------
__global__ void l2norm_kernel(const float* __restrict__ in, float* __restrict__ out)
{
    int r = blockIdx.x;
    int t = threadIdx.x;
    long i0 = (long)r * 512 + t;
    const long P = (long)NB2 * 512;
    float v0 = in[i0]       + in[i0 + P]       + in[i0 + 2*P]       + in[i0 + 3*P];
    float v1 = in[i0 + 256] + in[i0 + P + 256] + in[i0 + 2*P + 256] + in[i0 + 3*P + 256];
    float s = v0 * v0 + v1 * v1;
    #pragma unroll
    for (int o = 32; o > 0; o >>= 1) s += __shfl_down(s, o, 64);
    __shared__ float wsum[4];
    if ((t & 63) == 0) wsum[t >> 6] = s;
    __syncthreads();
    float tot = wsum[0] + wsum[1] + wsum[2] + wsum[3];
    float inv = rsqrtf(fmaxf(tot, 1e-12f));
    out[r * 512 + t] = v0 * inv;
    out[r * 512 + 256 + t] = v1 * inv;
}

extern "C" void kernel_launch(void* const* d_in, const int* in_sizes, int n_in,
                              void* d_out, int out_size, void* d_ws, size_t ws_size,
                              hipStream_t stream)
{
    const float* features = (const float*)d_in[0];
    const float* Ws1      = (const float*)d_in[1];
    const float* Wn1      = (const float*)d_in[2];
    const float* Ws2      = (const float*)d_in[3];
    const float* Wn2      = (const float*)d_in[4];
    const int*   adj      = (const int*)d_in[5];
    const int*   batch1   = (const int*)d_in[6];
    const int*   batch2   = (const int*)d_in[7];
    const int*   col1     = (const int*)d_in[8];
    const int*   col2     = (const int*)d_in[9];
    float* out = (float*)d_out;

    char* w = (char*)d_ws;
    auto alloc = [&](size_t bytes) {
        char* p = w;
        w += (bytes + 255) & ~(size_t)255;
        return p;
    };
    int*    nodes = (int*)alloc((size_t)NB2 * 4);
    int*    s1    = (int*)alloc((size_t)NB2 * FS1 * 4);
    int*    s2    = (int*)alloc((size_t)NB2 * FS1 * FS2 * 4);
    ushort* nm1   = (ushort*)alloc((size_t)NB2 * FD * 2);            // bf16 [1024,256]
    ushort* nm2   = (ushort*)alloc((size_t)NB2 * FS1 * FD * 2);      // bf16 [10240,256]
    ushort* h0n   = (ushort*)alloc((size_t)NB2 * 512 * 2);           // bf16 [1024,512]
    ushort* h1n   = (ushort*)alloc((size_t)NB2 * FS1 * 512 * 2);     // bf16 [10240,512]
    ushort* ml2   = (ushort*)alloc((size_t)NB2 * 512 * 2);           // bf16 [1024,512]
    float*  opre  = (float*)alloc((size_t)4 * NB2 * 512 * 4);        // fp32 [4][1024][512]
    ushort* Wt_s1 = (ushort*)alloc((size_t)FD * FH * 2);             // [256][256] n-major
    ushort* Wt_n1 = (ushort*)alloc((size_t)FD * FH * 2);
    ushort* Wt_s2 = (ushort*)alloc((size_t)512 * FH * 2);            // [256][512] n-major
    ushort* Wt_n2 = (ushort*)alloc((size_t)512 * FH * 2);

    // K1: weight transpose/cast + sampling
    prep_kernel<<<2536, 256, 0, stream>>>(Ws1, Wn1, Ws2, Wn2,
                                          Wt_s1, Wt_n1, Wt_s2, Wt_n2,
                                          batch1, batch2, adj, col1, col2,
                                          nodes, s1, s2);

    // K2: gather means + layer-1 self GEMMs (co-scheduled, independent)
    k2_means_l1self<<<3520, 256, 0, stream>>>(features, s2, s1, nodes,
                                              nm2, nm1, Wt_s1, h1n, h0n);

    // K3: layer-1 neigh GEMMs
    k3_l1neigh<<<704, 256, 0, stream>>>(nm2, nm1, Wt_n1, h1n, h0n);

    // K4: layer-2 neighbor mean + layer-2 self GEMM (co-scheduled)
    k4_ml2_l2self<<<512, 256, 0, stream>>>(h1n, ml2, h0n, Wt_s2, opre);

    // K5: layer-2 neigh GEMM
    k5_l2neigh<<<256, 256, 0, stream>>>(ml2, Wt_n2, opre);

    // K6: L2 normalize (sums partials) -> output
    l2norm_kernel<<<NB2, 256, 0, stream>>>(opre, out);
}